// Round 8
// baseline (194.318 us; speedup 1.0000x reference)
//
#include <hip/hip_runtime.h>

#define N 2048
#define DIM 64
#define NB 2048
#define PD_RANGE 1024.0f      // fixed hist range; pd <= 4*max||x||^2 ~ 520 << 1024
#define LOG_N 7.624618986159398f

typedef short bf16x8 __attribute__((ext_vector_type(8)));
typedef float f32x4 __attribute__((ext_vector_type(4)));
typedef unsigned short u16x8 __attribute__((ext_vector_type(8)));

// ws layout (bytes). [0, ZEND) is zeroed by prep_k every launch.
#define GHIST_OFF 0           // u32[2048]                     8192
#define SCAL_OFF  8192        // f32[2]: inv_hh, thh  (written by hist_k fan-in)
#define CNTH_OFF  8256        // u32 hist fan-in counter
#define CNTT_OFF  8320        // u32[128] per-i-tile fan-in counters
#define RS_OFF    8832        // f32[2048]
#define P1_OFF    17024       // f32[2048*64]                  524288
#define P2_OFF    541312      // f32[2048*64]                  524288
#define ZEND      1065600
#define ZWORDS    266400      // ZEND/4
#define SQ_OFF    1065600     // f32[2048]
#define XB_OFF    1073792     // bf16 XB[N][64] row-major
#define WT_OFF    1335936     // bf16 WT[16][64][128] (d-major)
#define XT_OFF    1598080     // bf16 XT[16][64][128]

__device__ inline float wred64(float v) {
    #pragma unroll
    for (int m = 32; m; m >>= 1) v += __shfl_xor(v, m, 64);
    return v;
}
__device__ inline unsigned short f2bf(float f) {
    unsigned u = __float_as_uint(f);
    return (unsigned short)((u + 0x7FFFu + ((u >> 16) & 1u)) >> 16);
}

// ---------------- prep: zero accumulator zone; sq, w, bf16 X copies ----------------
__global__ __launch_bounds__(256) void prep_k(const float* __restrict__ x,
                                              const float* __restrict__ mu,
                                              char* __restrict__ ws) {
    unsigned short* XB = (unsigned short*)(ws + XB_OFF);
    unsigned short* WT = (unsigned short*)(ws + WT_OFF);
    unsigned short* XT = (unsigned short*)(ws + XT_OFF);
    float* SQ = (float*)(ws + SQ_OFF);
    unsigned gtid = blockIdx.x * 256 + threadIdx.x;
    for (unsigned q = gtid; q < ZWORDS; q += 131072u) ((unsigned*)ws)[q] = 0u;
    int w = threadIdx.x >> 6, lane = threadIdx.x & 63;
    int j = blockIdx.x * 4 + w;
    float xv = x[j * DIM + lane];
    float sg = mu[lane] - xv;                       // s_grad
    float sq = wred64(xv * xv);
    float xd = wred64(xv * sg);
    float wv = sg - xv * (xd / sq) - xv * (63.0f / sq);  // D_j s_grad + divD_j
    XB[j * DIM + lane] = f2bf(xv);
    int bo = ((j >> 7) * DIM + lane) * 128 + (j & 127);  // [jt][d][jl]
    XT[bo] = f2bf(xv);
    WT[bo] = f2bf(wv);
    if (lane == 0) SQ[j] = sq;
}

// ---------------- histogram (rows subsampled by 4) + fan-in median scan ----------------
__global__ __launch_bounds__(256) void hist_k(char* __restrict__ ws) {
    __shared__ unsigned short s_xi[128 * 64];
    __shared__ unsigned short s_xj[64 * 64];
    __shared__ float s_sqi[128];
    __shared__ float s_sqj[64];
    __shared__ unsigned s_hist[NB];
    __shared__ unsigned s_flag;
    __shared__ float medv[2];
    const unsigned short* XB = (const unsigned short*)(ws + XB_OFF);
    const float* SQ = (const float*)(ws + SQ_OFF);
    unsigned* ghist = (unsigned*)(ws + GHIST_OFF);
    unsigned* cnth = (unsigned*)(ws + CNTH_OFF);
    float* scal_f = (float*)(ws + SCAL_OFF);
    int tid = threadIdx.x;
    int i0 = (blockIdx.x >> 5) * 128;             // sampled-row base (rows = 4*r)
    int j0 = (blockIdx.x & 31) * 64;
    for (int b = tid; b < NB; b += 256) s_hist[b] = 0u;
    const u16x8* XBv = (const u16x8*)XB;
    #pragma unroll
    for (int q = 0; q < 4; q++) {
        int idx = tid + q * 256; int r = idx >> 3, c = idx & 7;
        u16x8 v = XBv[(4 * (i0 + r)) * 8 + c];
        int byt = (c * 16) ^ ((r & 7) << 4);
        *(u16x8*)((char*)s_xi + r * 128 + byt) = v;
    }
    #pragma unroll
    for (int q = 0; q < 2; q++) {
        int idx = tid + q * 256; int r = idx >> 3, c = idx & 7;
        u16x8 v = XBv[(j0 + r) * 8 + c];
        int byt = (c * 16) ^ ((r & 7) << 4);
        *(u16x8*)((char*)s_xj + r * 128 + byt) = v;
    }
    if (tid < 128) s_sqi[tid] = SQ[4 * (i0 + tid)];
    if (tid >= 128 && tid < 192) s_sqj[tid - 128] = SQ[j0 + tid - 128];
    const float scale = (float)NB / PD_RANGE;
    __syncthreads();
    int lane = tid & 63, w = tid >> 6, lo = lane & 15, hi = lane >> 4;
    f32x4 acc[2][4];
    #pragma unroll
    for (int a = 0; a < 2; a++)
        #pragma unroll
        for (int b = 0; b < 4; b++) acc[a][b] = (f32x4)0.0f;
    #pragma unroll
    for (int kc = 0; kc < 2; kc++) {
        bf16x8 af[2];
        #pragma unroll
        for (int si = 0; si < 2; si++) {
            int row = w * 32 + si * 16 + lo;
            int byt = (kc * 64 + hi * 16) ^ ((row & 7) << 4);
            af[si] = *(const bf16x8*)((const char*)s_xi + row * 128 + byt);
        }
        #pragma unroll
        for (int sj = 0; sj < 4; sj++) {
            int row = sj * 16 + lo;
            int byt = (kc * 64 + hi * 16) ^ ((row & 7) << 4);
            bf16x8 bfr = *(const bf16x8*)((const char*)s_xj + row * 128 + byt);
            #pragma unroll
            for (int si = 0; si < 2; si++)
                acc[si][sj] = __builtin_amdgcn_mfma_f32_16x16x32_bf16(af[si], bfr, acc[si][sj], 0, 0, 0);
        }
    }
    #pragma unroll
    for (int si = 0; si < 2; si++)
        #pragma unroll
        for (int sj = 0; sj < 4; sj++)
            #pragma unroll
            for (int r = 0; r < 4; r++) {
                int il = w * 32 + si * 16 + hi * 4 + r;
                int jl = sj * 16 + lo;
                float pd = fmaxf(s_sqi[il] + s_sqj[jl] - 2.0f * acc[si][sj][r], 0.0f);
                int bin = min((int)(pd * scale), NB - 1);
                atomicAdd(&s_hist[bin], 1u);
            }
    __syncthreads();
    for (int b = tid; b < NB; b += 256) { unsigned v = s_hist[b]; if (v) atomicAdd(&ghist[b], v); }
    // ---- fan-in: last block computes median -> 1/hh, 2/hh ----
    __threadfence();
    if (tid == 0) s_flag = atomicAdd(cnth, 1u);
    __syncthreads();
    if (s_flag == 127u) {
        __threadfence();
        unsigned v[8]; unsigned s = 0;
        #pragma unroll
        for (int b = 0; b < 8; b++) { v[b] = ghist[tid * 8 + b]; s += v[b]; }
        unsigned* csum = s_hist;                    // reuse (post-barrier)
        csum[tid] = s;
        __syncthreads();
        #pragma unroll
        for (int off = 1; off < 256; off <<= 1) {
            unsigned t = (tid >= off) ? csum[tid - off] : 0u;
            __syncthreads();
            csum[tid] += t;
            __syncthreads();
        }
        unsigned incl = csum[tid], excl = incl - s;
        const float binw = PD_RANGE / (float)NB;
        const unsigned kqs[2] = { 524287u, 524288u };  // 2^20/2 - 1, 2^20/2
        #pragma unroll
        for (int t = 0; t < 2; t++) {
            unsigned kq = kqs[t];
            if (excl <= kq && kq < incl) {
                unsigned a2 = excl; int bin = -1;
                #pragma unroll
                for (int b = 0; b < 8; b++) {
                    unsigned na = a2 + v[b];
                    if (bin < 0 && na > kq) bin = tid * 8 + b;
                    a2 = na;
                }
                medv[t] = ((float)bin + 0.5f) * binw;
            }
        }
        __syncthreads();
        if (tid == 0) {
            float hh = 0.5f * (medv[0] + medv[1]) / LOG_N + 1e-6f;
            scal_f[0] = 1.0f / hh;
            scal_f[1] = 2.0f / hh;
        }
    }
}

// ---------------- main SVGD pass: 16 real rows x j-quarter, fan-in epilogue ----------------
__global__ __launch_bounds__(512) void svgd_k(const float* __restrict__ x,
                                              char* __restrict__ ws,
                                              float* __restrict__ out) {
    __shared__ unsigned short s_k[16 * 256];     // 8 KB (intra-wave K shuffle)
    __shared__ unsigned short s_c[16 * 256];     // 8 KB
    __shared__ float s_red[2 * 16 * 64];         // 8 KB (cross-wave reduction)
    __shared__ float s_rs[16];
    __shared__ unsigned s_flag;
    const unsigned short* XB = (const unsigned short*)(ws + XB_OFF);
    const char* WTb = ws + WT_OFF;
    const char* XTb = ws + XT_OFF;
    const float* SQ = (const float*)(ws + SQ_OFF);
    const float* scal_f = (const float*)(ws + SCAL_OFF);
    float* P1 = (float*)(ws + P1_OFF);
    float* P2 = (float*)(ws + P2_OFF);
    float* RS = (float*)(ws + RS_OFF);
    unsigned* cntt = (unsigned*)(ws + CNTT_OFF);
    int tid = threadIdx.x;
    int it = blockIdx.x >> 2, jq = blockIdx.x & 3;
    int i0 = it * 16;
    int lane = tid & 63, w = tid >> 6, lo = lane & 15, hi = lane >> 4;

    for (int q = tid; q < 2 * 16 * 64; q += 512) s_red[q] = 0.f;
    if (tid < 16) s_rs[tid] = 0.f;
    __syncthreads();

    float inv_hh = scal_f[0], thh = scal_f[1];
    float sqi_r[4];
    #pragma unroll
    for (int r = 0; r < 4; r++) sqi_r[r] = SQ[i0 + hi * 4 + r];
    bf16x8 af[2];
    #pragma unroll
    for (int kc = 0; kc < 2; kc++)
        af[kc] = *(const bf16x8*)(XB + (i0 + lo) * 64 + kc * 32 + hi * 8);

    f32x4 a1[4], a2[4], rsv;
    #pragma unroll
    for (int sd = 0; sd < 4; sd++) { a1[sd] = (f32x4)0.f; a2[sd] = (f32x4)0.f; }
    rsv = (f32x4)0.f;
    bf16x8 ones;
    #pragma unroll
    for (int e = 0; e < 8; e++) ones[e] = (short)0x3F80;

    // ---- main loop: 2 iters x 256 j (8 waves x 32 j each) over this j-quarter ----
    for (int itr = 0; itr < 2; itr++) {
        int jw = jq * 512 + itr * 256 + w * 32;     // this wave's 32-j slice
        bf16x8 bS[2][2];
        #pragma unroll
        for (int sj = 0; sj < 2; sj++)
            #pragma unroll
            for (int kc = 0; kc < 2; kc++)
                bS[sj][kc] = *(const bf16x8*)(XB + (jw + sj * 16 + lo) * 64 + kc * 32 + hi * 8);
        float sqj[2];
        sqj[0] = SQ[jw + lo];
        sqj[1] = SQ[jw + 16 + lo];
        int jt = jw >> 7;
        const char* wtb = WTb + jt * 16384;
        const char* xtb = XTb + jt * 16384;
        bf16x8 bW[4], bX[4];
        #pragma unroll
        for (int sd = 0; sd < 4; sd++) {
            int off = (sd * 16 + lo) * 256 + (w & 3) * 64 + hi * 16;
            bW[sd] = *(const bf16x8*)(wtb + off);
            bX[sd] = *(const bf16x8*)(xtb + off);
        }
        // S = X_I . X_J^T
        f32x4 sreg[2]; sreg[0] = (f32x4)0.f; sreg[1] = (f32x4)0.f;
        #pragma unroll
        for (int kc = 0; kc < 2; kc++)
            #pragma unroll
            for (int sj = 0; sj < 2; sj++)
                sreg[sj] = __builtin_amdgcn_mfma_f32_16x16x32_bf16(af[kc], bS[sj][kc], sreg[sj], 0, 0, 0);
        // K, C -> bf16 -> LDS (intra-wave re-layout; read-XOR == write-XOR, no barrier)
        #pragma unroll
        for (int sj = 0; sj < 2; sj++) {
            float rq = 1.0f / sqj[sj];
            #pragma unroll
            for (int r = 0; r < 4; r++) {
                int il = hi * 4 + r;
                float dot = sreg[sj][r];
                float pd = fmaxf(sqi_r[r] + sqj[sj] - 2.0f * dot, 0.0f);
                float kv = __expf(-pd * inv_hh);
                float cv = kv * dot * rq;
                int byt = (w * 64 + sj * 32 + lo * 2) ^ ((il & 7) << 4);
                *(unsigned short*)((char*)s_k + il * 512 + byt) = f2bf(kv);
                *(unsigned short*)((char*)s_c + il * 512 + byt) = f2bf(cv);
            }
        }
        int bytK = (w * 64 + hi * 16) ^ ((lo & 7) << 4);
        bf16x8 aK = *(const bf16x8*)((const char*)s_k + lo * 512 + bytK);
        bf16x8 aC = *(const bf16x8*)((const char*)s_c + lo * 512 + bytK);
        // acc1 += K.W, acc2 += C.X, rs += K.1
        #pragma unroll
        for (int sd = 0; sd < 4; sd++) {
            a1[sd] = __builtin_amdgcn_mfma_f32_16x16x32_bf16(aK, bW[sd], a1[sd], 0, 0, 0);
            a2[sd] = __builtin_amdgcn_mfma_f32_16x16x32_bf16(aC, bX[sd], a2[sd], 0, 0, 0);
        }
        rsv = __builtin_amdgcn_mfma_f32_16x16x32_bf16(aK, ones, rsv, 0, 0, 0);
    }

    // ---- cross-wave LDS reduction ----
    #pragma unroll
    for (int sd = 0; sd < 4; sd++)
        #pragma unroll
        for (int r = 0; r < 4; r++) {
            int il = hi * 4 + r, dd = sd * 16 + lo;
            atomicAdd(&s_red[il * 64 + dd], a1[sd][r]);
            atomicAdd(&s_red[16 * 64 + il * 64 + dd], a2[sd][r]);
        }
    if (lo == 0) {
        #pragma unroll
        for (int r = 0; r < 4; r++) atomicAdd(&s_rs[hi * 4 + r], rsv[r]);
    }
    __syncthreads();

    // ---- push partials to global (split-K accumulate) ----
    for (int q = tid; q < 16 * 64; q += 512) {
        int row = q >> 6, dd = q & 63;
        atomicAdd(&P1[(i0 + row) * 64 + dd], s_red[q]);
        atomicAdd(&P2[(i0 + row) * 64 + dd], s_red[16 * 64 + q]);
    }
    if (tid < 16) atomicAdd(&RS[i0 + tid], s_rs[tid]);

    // ---- fan-in: 4th arriving quarter runs the epilogue for this i-tile ----
    __threadfence();
    if (tid == 0) s_flag = atomicAdd(&cntt[it], 1u);
    __syncthreads();
    if (s_flag == 3u) {
        __threadfence();
        #pragma unroll
        for (int rr = 0; rr < 2; rr++) {
            int row = i0 + w * 2 + rr;              // 8 waves x 2 rows = 16
            float xv = x[row * DIM + lane];
            float sqi = SQ[row];
            float acc1 = P1[row * 64 + lane];
            float acc2 = P2[row * 64 + lane];
            float rs = RS[row];
            float inner = acc1 + (rs * xv - acc2) * thh;
            float xin = wred64(xv * inner);
            float gr = inner - xv * ((xin + 63.0f) / sqi);
            float dx = gr * (0.1f / (float)N);
            dx = fminf(fmaxf(dx, -1000.0f), 1000.0f);
            out[row * DIM + lane] = xv + dx;
        }
    }
}

extern "C" void kernel_launch(void* const* d_in, const int* in_sizes, int n_in,
                              void* d_out, int out_size, void* d_ws, size_t ws_size,
                              hipStream_t stream) {
    const float* x  = (const float*)d_in[0];
    const float* mu = (const float*)d_in[1];
    float* out = (float*)d_out;
    char* ws = (char*)d_ws;

    prep_k<<<N / 4, 256, 0, stream>>>(x, mu, ws);
    hist_k<<<(512 / 128) * (N / 64), 256, 0, stream>>>(ws);
    svgd_k<<<(N / 16) * 4, 512, 0, stream>>>(x, ws, out);
}

// Round 9
// 104.552 us; speedup vs baseline: 1.8586x; 1.8586x over previous
//
#include <hip/hip_runtime.h>

#define N 2048
#define DIM 64
#define NB 2048
#define PD_RANGE 1024.0f      // fixed hist range; pd <= 4*max||x||^2 ~ 520 << 1024
#define LOG_N 7.624618986159398f

typedef short bf16x8 __attribute__((ext_vector_type(8)));
typedef float f32x4 __attribute__((ext_vector_type(4)));
typedef unsigned short u16x8 __attribute__((ext_vector_type(8)));

// ws layout (bytes)
#define GHIST_OFF 0           // u32[2048]  (zeroed by prep blocks 0-7)
#define SCAL_OFF  8192        // f32[2]: inv_hh, thh (written by hist_k fan-in)
#define CNTH_OFF  8256        // u32 hist fan-in counter (zeroed by prep block 8)
#define SQ_OFF    8448        // f32[2048]
#define XB_OFF    16640       // bf16 XB[N][64] row-major       (262144)
#define WT_OFF    278784      // bf16 WT[16][64][128] (d-major) (262144)
#define XT_OFF    540928      // bf16 XT[16][64][128]           (262144)

__device__ inline float wred64(float v) {
    #pragma unroll
    for (int m = 32; m; m >>= 1) v += __shfl_xor(v, m, 64);
    return v;
}
__device__ inline unsigned short f2bf(float f) {
    unsigned u = __float_as_uint(f);
    return (unsigned short)((u + 0x7FFFu + ((u >> 16) & 1u)) >> 16);
}

// ---------------- prep: zero hist/counter; sq, w, bf16 X copies ----------------
__global__ __launch_bounds__(256) void prep_k(const float* __restrict__ x,
                                              const float* __restrict__ mu,
                                              char* __restrict__ ws) {
    unsigned short* XB = (unsigned short*)(ws + XB_OFF);
    unsigned short* WT = (unsigned short*)(ws + WT_OFF);
    unsigned short* XT = (unsigned short*)(ws + XT_OFF);
    float* SQ = (float*)(ws + SQ_OFF);
    unsigned* ghist = (unsigned*)(ws + GHIST_OFF);
    if (blockIdx.x < 8) ghist[blockIdx.x * 256 + threadIdx.x] = 0u;
    if (blockIdx.x == 8 && threadIdx.x == 0) *(unsigned*)(ws + CNTH_OFF) = 0u;
    int w = threadIdx.x >> 6, lane = threadIdx.x & 63;
    int j = blockIdx.x * 4 + w;
    float xv = x[j * DIM + lane];
    float sg = mu[lane] - xv;                       // s_grad
    float sq = wred64(xv * xv);
    float xd = wred64(xv * sg);
    float wv = sg - xv * (xd / sq) - xv * (63.0f / sq);  // D_j s_grad + divD_j
    XB[j * DIM + lane] = f2bf(xv);
    int bo = ((j >> 7) * DIM + lane) * 128 + (j & 127);  // [jt][d][jl]
    XT[bo] = f2bf(xv);
    WT[bo] = f2bf(wv);
    if (lane == 0) SQ[j] = sq;
}

// ---------------- histogram (rows subsampled by 4) + fan-in median scan ----------------
__global__ __launch_bounds__(256) void hist_k(char* __restrict__ ws) {
    __shared__ unsigned short s_xi[128 * 64];
    __shared__ unsigned short s_xj[64 * 64];
    __shared__ float s_sqi[128];
    __shared__ float s_sqj[64];
    __shared__ unsigned s_hist[NB];
    __shared__ unsigned s_flag;
    __shared__ float medv[2];
    const unsigned short* XB = (const unsigned short*)(ws + XB_OFF);
    const float* SQ = (const float*)(ws + SQ_OFF);
    unsigned* ghist = (unsigned*)(ws + GHIST_OFF);
    unsigned* cnth = (unsigned*)(ws + CNTH_OFF);
    float* scal_f = (float*)(ws + SCAL_OFF);
    int tid = threadIdx.x;
    int i0 = (blockIdx.x >> 5) * 128;             // sampled-row base (rows = 4*r)
    int j0 = (blockIdx.x & 31) * 64;
    for (int b = tid; b < NB; b += 256) s_hist[b] = 0u;
    const u16x8* XBv = (const u16x8*)XB;
    #pragma unroll
    for (int q = 0; q < 4; q++) {
        int idx = tid + q * 256; int r = idx >> 3, c = idx & 7;
        u16x8 v = XBv[(4 * (i0 + r)) * 8 + c];
        int byt = (c * 16) ^ ((r & 7) << 4);
        *(u16x8*)((char*)s_xi + r * 128 + byt) = v;
    }
    #pragma unroll
    for (int q = 0; q < 2; q++) {
        int idx = tid + q * 256; int r = idx >> 3, c = idx & 7;
        u16x8 v = XBv[(j0 + r) * 8 + c];
        int byt = (c * 16) ^ ((r & 7) << 4);
        *(u16x8*)((char*)s_xj + r * 128 + byt) = v;
    }
    if (tid < 128) s_sqi[tid] = SQ[4 * (i0 + tid)];
    if (tid >= 128 && tid < 192) s_sqj[tid - 128] = SQ[j0 + tid - 128];
    const float scale = (float)NB / PD_RANGE;
    __syncthreads();
    int lane = tid & 63, w = tid >> 6, lo = lane & 15, hi = lane >> 4;
    f32x4 acc[2][4];
    #pragma unroll
    for (int a = 0; a < 2; a++)
        #pragma unroll
        for (int b = 0; b < 4; b++) acc[a][b] = (f32x4)0.0f;
    #pragma unroll
    for (int kc = 0; kc < 2; kc++) {
        bf16x8 af[2];
        #pragma unroll
        for (int si = 0; si < 2; si++) {
            int row = w * 32 + si * 16 + lo;
            int byt = (kc * 64 + hi * 16) ^ ((row & 7) << 4);
            af[si] = *(const bf16x8*)((const char*)s_xi + row * 128 + byt);
        }
        #pragma unroll
        for (int sj = 0; sj < 4; sj++) {
            int row = sj * 16 + lo;
            int byt = (kc * 64 + hi * 16) ^ ((row & 7) << 4);
            bf16x8 bfr = *(const bf16x8*)((const char*)s_xj + row * 128 + byt);
            #pragma unroll
            for (int si = 0; si < 2; si++)
                acc[si][sj] = __builtin_amdgcn_mfma_f32_16x16x32_bf16(af[si], bfr, acc[si][sj], 0, 0, 0);
        }
    }
    #pragma unroll
    for (int si = 0; si < 2; si++)
        #pragma unroll
        for (int sj = 0; sj < 4; sj++)
            #pragma unroll
            for (int r = 0; r < 4; r++) {
                int il = w * 32 + si * 16 + hi * 4 + r;
                int jl = sj * 16 + lo;
                float pd = fmaxf(s_sqi[il] + s_sqj[jl] - 2.0f * acc[si][sj][r], 0.0f);
                int bin = min((int)(pd * scale), NB - 1);
                atomicAdd(&s_hist[bin], 1u);
            }
    __syncthreads();
    for (int b = tid; b < NB; b += 256) { unsigned v = s_hist[b]; if (v) atomicAdd(&ghist[b], v); }
    // ---- fan-in: last block computes median -> 1/hh, 2/hh ----
    __threadfence();
    if (tid == 0) s_flag = atomicAdd(cnth, 1u);
    __syncthreads();
    if (s_flag == 127u) {
        __threadfence();
        unsigned v[8]; unsigned s = 0;
        #pragma unroll
        for (int b = 0; b < 8; b++) { v[b] = ghist[tid * 8 + b]; s += v[b]; }
        unsigned* csum = s_hist;                    // reuse (post-barrier)
        csum[tid] = s;
        __syncthreads();
        #pragma unroll
        for (int off = 1; off < 256; off <<= 1) {
            unsigned t = (tid >= off) ? csum[tid - off] : 0u;
            __syncthreads();
            csum[tid] += t;
            __syncthreads();
        }
        unsigned incl = csum[tid], excl = incl - s;
        const float binw = PD_RANGE / (float)NB;
        const unsigned kqs[2] = { 524287u, 524288u };  // 2^20/2 - 1, 2^20/2
        #pragma unroll
        for (int t = 0; t < 2; t++) {
            unsigned kq = kqs[t];
            if (excl <= kq && kq < incl) {
                unsigned a2 = excl; int bin = -1;
                #pragma unroll
                for (int b = 0; b < 8; b++) {
                    unsigned na = a2 + v[b];
                    if (bin < 0 && na > kq) bin = tid * 8 + b;
                    a2 = na;
                }
                medv[t] = ((float)bin + 0.5f) * binw;
            }
        }
        __syncthreads();
        if (tid == 0) {
            float hh = 0.5f * (medv[0] + medv[1]) / LOG_N + 1e-6f;
            scal_f[0] = 1.0f / hh;
            scal_f[1] = 2.0f / hh;
        }
    }
}

// ---------------- fused SVGD: R7 structure + software-pipelined j-loop ----------------
__global__ __launch_bounds__(512) void svgd_k(const float* __restrict__ x,
                                              char* __restrict__ ws,
                                              float* __restrict__ out) {
    __shared__ unsigned short s_k[16 * 256];     // 8 KB (intra-wave K shuffle)
    __shared__ unsigned short s_c[16 * 256];     // 8 KB
    __shared__ float s_red[2 * 8 * 64];          // 4 KB (cross-wave reduction)
    __shared__ float s_rs[8];
    const unsigned short* XB = (const unsigned short*)(ws + XB_OFF);
    const char* WTb = ws + WT_OFF;
    const char* XTb = ws + XT_OFF;
    const float* SQ = (const float*)(ws + SQ_OFF);
    const float* scal_f = (const float*)(ws + SCAL_OFF);
    int tid = threadIdx.x;
    int i0 = blockIdx.x * 8;
    int lane = tid & 63, w = tid >> 6, lo = lane & 15, hi = lane >> 4;

    for (int q = tid; q < 2 * 8 * 64; q += 512) s_red[q] = 0.f;
    if (tid < 8) s_rs[tid] = 0.f;

    float inv_hh = scal_f[0], thh = scal_f[1];
    float sqi_r[4];
    #pragma unroll
    for (int r = 0; r < 4; r++) { int il = hi * 4 + r; sqi_r[r] = (il < 8) ? SQ[i0 + il] : 0.0f; }
    bf16x8 af[2];
    #pragma unroll
    for (int kc = 0; kc < 2; kc++)
        af[kc] = (lo < 8) ? *(const bf16x8*)(XB + (i0 + lo) * 64 + kc * 32 + hi * 8) : (bf16x8)0;

    f32x4 a1[4], a2[4], rsv;
    #pragma unroll
    for (int sd = 0; sd < 4; sd++) { a1[sd] = (f32x4)0.f; a2[sd] = (f32x4)0.f; }
    rsv = (f32x4)0.f;
    bf16x8 ones;
    #pragma unroll
    for (int e = 0; e < 8; e++) ones[e] = (short)0x3F80;
    __syncthreads();                              // s_red init visible

#define LOADJ(BS, SQJ, BW, BX, jw) do { \
    _Pragma("unroll") \
    for (int sj = 0; sj < 2; sj++) \
        _Pragma("unroll") \
        for (int kc = 0; kc < 2; kc++) \
            BS[sj][kc] = *(const bf16x8*)(XB + ((jw) + sj * 16 + lo) * 64 + kc * 32 + hi * 8); \
    SQJ[0] = SQ[(jw) + lo]; \
    SQJ[1] = SQ[(jw) + 16 + lo]; \
    { int _jt = (jw) >> 7; \
      const char* _wtb = WTb + _jt * 16384; \
      const char* _xtb = XTb + _jt * 16384; \
      _Pragma("unroll") \
      for (int sd = 0; sd < 4; sd++) { \
          int _off = (sd * 16 + lo) * 256 + ((jw) & 127) * 2 + hi * 16; \
          BW[sd] = *(const bf16x8*)(_wtb + _off); \
          BX[sd] = *(const bf16x8*)(_xtb + _off); } } \
} while (0)

#define COMPUTE(BS, SQJ, BW, BX) do { \
    f32x4 sreg[2]; sreg[0] = (f32x4)0.f; sreg[1] = (f32x4)0.f; \
    _Pragma("unroll") \
    for (int kc = 0; kc < 2; kc++) \
        _Pragma("unroll") \
        for (int sj = 0; sj < 2; sj++) \
            sreg[sj] = __builtin_amdgcn_mfma_f32_16x16x32_bf16(af[kc], BS[sj][kc], sreg[sj], 0, 0, 0); \
    _Pragma("unroll") \
    for (int sj = 0; sj < 2; sj++) { \
        float rq = 1.0f / SQJ[sj]; \
        _Pragma("unroll") \
        for (int r = 0; r < 4; r++) { \
            int il = hi * 4 + r; \
            float dot = sreg[sj][r]; \
            float pd = fmaxf(sqi_r[r] + SQJ[sj] - 2.0f * dot, 0.0f); \
            float kv = __expf(-pd * inv_hh); \
            float cv = kv * dot * rq; \
            int byt = (w * 64 + sj * 32 + lo * 2) ^ ((il & 7) << 4); \
            *(unsigned short*)((char*)s_k + il * 512 + byt) = f2bf(kv); \
            *(unsigned short*)((char*)s_c + il * 512 + byt) = f2bf(cv); \
        } \
    } \
    { int bytK = (w * 64 + hi * 16) ^ ((lo & 7) << 4); \
      bf16x8 aK = *(const bf16x8*)((const char*)s_k + lo * 512 + bytK); \
      bf16x8 aC = *(const bf16x8*)((const char*)s_c + lo * 512 + bytK); \
      _Pragma("unroll") \
      for (int sd = 0; sd < 4; sd++) { \
          a1[sd] = __builtin_amdgcn_mfma_f32_16x16x32_bf16(aK, BW[sd], a1[sd], 0, 0, 0); \
          a2[sd] = __builtin_amdgcn_mfma_f32_16x16x32_bf16(aC, BX[sd], a2[sd], 0, 0, 0); \
      } \
      rsv = __builtin_amdgcn_mfma_f32_16x16x32_bf16(aK, ones, rsv, 0, 0, 0); } \
} while (0)

    // ---- 8 iters x 256 j (8 waves x 32 j), ping-pong register double-buffer ----
    bf16x8 bSa[2][2], bWa[4], bXa[4]; float sqa[2];
    bf16x8 bSb[2][2], bWb[4], bXb[4]; float sqb[2];
    LOADJ(bSa, sqa, bWa, bXa, w * 32);            // it = 0
    for (int m = 0; m < 4; m++) {
        int it0 = 2 * m;
        LOADJ(bSb, sqb, bWb, bXb, (it0 + 1) * 256 + w * 32);
        COMPUTE(bSa, sqa, bWa, bXa);
        if (m < 3) LOADJ(bSa, sqa, bWa, bXa, (it0 + 2) * 256 + w * 32);
        COMPUTE(bSb, sqb, bWb, bXb);
    }
#undef LOADJ
#undef COMPUTE

    // ---- cross-wave reduction (8 waves' disjoint j-slices) ----
    #pragma unroll
    for (int sd = 0; sd < 4; sd++)
        #pragma unroll
        for (int r = 0; r < 4; r++) {
            int il = hi * 4 + r;
            if (il < 8) {
                int dd = sd * 16 + lo;
                atomicAdd(&s_red[il * 64 + dd], a1[sd][r]);
                atomicAdd(&s_red[8 * 64 + il * 64 + dd], a2[sd][r]);
            }
        }
    if (lo == 0) {
        #pragma unroll
        for (int r = 0; r < 4; r++) {
            int il = hi * 4 + r;
            if (il < 8) atomicAdd(&s_rs[il], rsv[r]);
        }
    }
    __syncthreads();

    // ---- inline epilogue: wave w handles row i0+w, lane = d ----
    float xv = x[(i0 + w) * DIM + lane];
    float sqi = SQ[i0 + w];
    float acc1 = s_red[w * 64 + lane];
    float acc2 = s_red[8 * 64 + w * 64 + lane];
    float rs = s_rs[w];
    float inner = acc1 + (rs * xv - acc2) * thh;
    float xin = wred64(xv * inner);
    float gr = inner - xv * ((xin + 63.0f) / sqi);
    float dx = gr * (0.1f / (float)N);
    dx = fminf(fmaxf(dx, -1000.0f), 1000.0f);
    out[(i0 + w) * DIM + lane] = xv + dx;
}

extern "C" void kernel_launch(void* const* d_in, const int* in_sizes, int n_in,
                              void* d_out, int out_size, void* d_ws, size_t ws_size,
                              hipStream_t stream) {
    const float* x  = (const float*)d_in[0];
    const float* mu = (const float*)d_in[1];
    float* out = (float*)d_out;
    char* ws = (char*)d_ws;

    prep_k<<<N / 4, 256, 0, stream>>>(x, mu, ws);
    hist_k<<<(512 / 128) * (N / 64), 256, 0, stream>>>(ws);
    svgd_k<<<N / 8, 512, 0, stream>>>(x, ws, out);
}